// Round 2
// baseline (364.668 us; speedup 1.0000x reference)
//
#include <hip/hip_runtime.h>

#define BDIM 16384
#define IN_D 151
#define HID_D 200
#define CENT_D 2000

// padded dims
#define INP 192     // K of GEMM0
#define HIDP 256    // N of GEMM0, K of GEMM1
#define CENTP 2048  // N of GEMM1/2, K of GEMM2/3
#define KERNR 256   // padded rows for kern/centres

using bf16x8 = __attribute__((ext_vector_type(8))) short;
using f32x4  = __attribute__((ext_vector_type(4))) float;

__device__ __forceinline__ unsigned short f2bf(float f) {
  unsigned u = __builtin_bit_cast(unsigned, f);
  u += 0x7FFFu + ((u >> 16) & 1u);
  return (unsigned short)(u >> 16);
}
__device__ __forceinline__ float bf2f(unsigned short h) {
  unsigned u = ((unsigned)h) << 16;
  return __builtin_bit_cast(float, u);
}

typedef __attribute__((address_space(1))) const unsigned int guint;
typedef __attribute__((address_space(3))) unsigned int luint;
__device__ __forceinline__ void g2l16(const void* g, void* l) {
  __builtin_amdgcn_global_load_lds((guint*)g, (luint*)l, 16, 0, 0);
}

struct GArgs {
  const unsigned short* A;   // M x K bf16 row-major
  const unsigned short* B;   // N x K bf16 row-major
  int K;
  int kspan;                 // K-range per blockIdx.z (== K when no split)
  const float* x2; const float* c2; const float* sg2;  // MODE 0
  const float* bias;                                    // MODE 1,2
  unsigned short* obf; int ldo;                         // MODE 0,1,2
  float* of;                                            // MODE 3 (per-z slab)
};

// ---------------------------------------------------------------------------
// 128x128 tile, BK=64, 4 waves, 2-barrier structure (kept for GEMM0 / GEMM3).
// Supports split-K via blockIdx.z * kspan.
// ---------------------------------------------------------------------------
template<int MODE>
__global__ __launch_bounds__(256) void gemm_bt(GArgs p) {
  __shared__ __align__(16) short As[128 * 64];
  __shared__ __align__(16) short Bs[128 * 64];
  const int tid  = threadIdx.x;
  const int lane = tid & 63;
  const int w    = tid >> 6;
  const int wr   = w >> 1, wc = w & 1;
  const int lr   = lane & 15;
  const int tm = blockIdx.x, tn = blockIdx.y;
  const int K = p.K;
  const int kz = blockIdx.z;
  const int kbeg = kz * p.kspan;
  f32x4 acc[4][4] = {};

  const unsigned short* Ag = p.A + (size_t)tm * 128 * K;
  const unsigned short* Bg = p.B + (size_t)tn * 128 * K;

  int rowc[4], colc[4], ldsc[4];
#pragma unroll
  for (int i = 0; i < 4; i++) {
    int cc = i * 256 + tid;
    rowc[i] = cc >> 3;
    colc[i] = ((cc & 7) ^ (rowc[i] & 7)) * 8;
    ldsc[i] = cc * 8;
  }

  for (int k0 = kbeg; k0 < kbeg + p.kspan; k0 += 64) {
    __syncthreads();
#pragma unroll
    for (int i = 0; i < 4; i++)
      g2l16(Ag + (size_t)rowc[i] * K + k0 + colc[i], &As[ldsc[i]]);
#pragma unroll
    for (int i = 0; i < 4; i++)
      g2l16(Bg + (size_t)rowc[i] * K + k0 + colc[i], &Bs[ldsc[i]]);
    __syncthreads();
#pragma unroll
    for (int ks = 0; ks < 2; ks++) {
      bf16x8 af[4], bfr[4];
#pragma unroll
      for (int m = 0; m < 4; m++) {
        int r = wr * 64 + m * 16 + lr;
        af[m] = *(const bf16x8*)&As[r * 64 + ((((ks << 2) + (lane >> 4)) ^ (r & 7)) << 3)];
      }
#pragma unroll
      for (int n = 0; n < 4; n++) {
        int r = wc * 64 + n * 16 + lr;
        bfr[n] = *(const bf16x8*)&Bs[r * 64 + ((((ks << 2) + (lane >> 4)) ^ (r & 7)) << 3)];
      }
#pragma unroll
      for (int m = 0; m < 4; m++)
#pragma unroll
        for (int n = 0; n < 4; n++)
          acc[m][n] = __builtin_amdgcn_mfma_f32_16x16x32_bf16(af[m], bfr[n], acc[m][n], 0, 0, 0);
    }
  }

  const int rb = tm * 128 + wr * 64 + (lane >> 4) * 4;
  const int cb = tn * 128 + wc * 64 + lr;
#pragma unroll
  for (int m = 0; m < 4; m++) {
#pragma unroll
    for (int n = 0; n < 4; n++) {
#pragma unroll
      for (int r = 0; r < 4; r++) {
        const int gi = rb + m * 16 + r;
        const int gj = cb + n * 16;
        const float v = acc[m][n][r];
        if constexpr (MODE == 0) {
          float ph = 0.f;
          if (gj < HID_D) {
            float d2 = fmaxf(p.x2[gi] + p.c2[gj] - 2.f * v, 0.f);
            ph = __expf(-d2 * p.sg2[gj]);
          }
          p.obf[(size_t)gi * p.ldo + gj] = f2bf(ph);
        } else if constexpr (MODE == 3) {
          float* of = p.of + (size_t)kz * BDIM * IN_D;
          if (gj < IN_D) of[(size_t)gi * IN_D + gj] = v;
        }
      }
    }
  }
}

// ---------------------------------------------------------------------------
// 256x256 tile, BK=64, 8 waves (2Mx4N), 8-phase counted-vmcnt schedule.
// LDS 128 KiB (2 dbuf x (A 32KB + B 32KB)). Stage order per K-tile:
// [B r0..r3, A r0, A r2, A r1, A r3] so each global_load_lds of tile t+2
// lands in a region whose last ds_read retired >=1 closing barrier earlier.
// Pipeline: prologue issues tile0 (8 rounds) + tile1's first 6; steady state
// phase p issues 2 rounds; vmcnt(6) once per K-tile (3 half-tiles in flight).
// ---------------------------------------------------------------------------
template<int MODE>
__global__ __launch_bounds__(512, 2) void gemm256(GArgs p, int nbxs) {
  __shared__ __align__(16) short As[2][256 * 64];
  __shared__ __align__(16) short Bs[2][256 * 64];
  const int tid  = threadIdx.x;
  const int lane = tid & 63;
  const int w    = tid >> 6;
  const int wr   = w >> 2;      // 0..1  (128-row slice)
  const int wc   = w & 3;       // 0..3  (64-col slice)
  const int lr   = lane & 15;
  const int lg   = lane >> 4;   // 0..3
  const int K    = p.K;
  const int NT   = K >> 6;

  // XCD-aware swizzle (gridDim.x % 8 == 0): each XCD owns a contiguous chunk
  const int cpx = (int)gridDim.x >> 3;
  const int swz = ((int)blockIdx.x & 7) * cpx + ((int)blockIdx.x >> 3);
  const int tm = swz & ((1 << nbxs) - 1);
  const int tn = swz >> nbxs;

  const unsigned short* Ag = p.A + (size_t)tm * 256 * K;
  const unsigned short* Bg = p.B + (size_t)tn * 256 * K;

  f32x4 acc[8][4] = {};

  // stage round q of the global sequence (8 rounds per K-tile)
  auto stage_q = [&](int q) {
    if (q >= NT * 8) return;                 // uniform predicate
    const int tt  = q >> 3;
    const int p8  = q & 7;
    const int k0  = tt << 6;
    const int bsel = tt & 1;
    const int isA = p8 >> 2;
    // B: r = p8 (0..3);  A: p8 4..7 -> r {0,2,1,3}
    const int r = isA ? (((p8 & 1) << 1) | ((p8 >> 1) & 1)) : p8;
    const int cc  = (r << 9) + tid;          // 16B-chunk id in 256x64 tile
    const int row = cc >> 3, c8 = cc & 7;
    const size_t goff = (size_t)row * K + k0 + ((c8 ^ (row & 7)) << 3);
    if (isA) g2l16(Ag + goff, &As[bsel][cc << 3]);
    else     g2l16(Bg + goff, &Bs[bsel][cc << 3]);
  };

  // prologue: tile0 complete (8) + tile1's first 6 rounds
#pragma unroll
  for (int q = 0; q < 14; q++) stage_q(q);
  asm volatile("s_waitcnt vmcnt(6)" ::: "memory");
  asm volatile("s_barrier" ::: "memory");

  // LDS read column offsets (involution of the staged swizzle)
  const int jx0 = ((0 + lg) ^ (lr & 7)) << 3;
  const int jx1 = ((4 + lg) ^ (lr & 7)) << 3;
  const int arow = wr * 128 + lr;
  const int brow = wc * 64 + lr;

  int qb = 14;
  for (int t = 0; t < NT; ++t) {
    const short* Ab = &As[t & 1][0];
    const short* Bb = &Bs[t & 1][0];
    bf16x8 bfr[4][2];
#pragma unroll
    for (int ph = 0; ph < 4; ph++) {
      bf16x8 af[2][2];
#pragma unroll
      for (int mm = 0; mm < 2; mm++) {
        const int ra = (arow + (ph * 2 + mm) * 16) << 6;
        af[mm][0] = *(const bf16x8*)&Ab[ra + jx0];
        af[mm][1] = *(const bf16x8*)&Ab[ra + jx1];
      }
      if (ph == 0) {
#pragma unroll
        for (int n = 0; n < 4; n++) {
          const int rb_ = (brow + n * 16) << 6;
          bfr[n][0] = *(const bf16x8*)&Bb[rb_ + jx0];
          bfr[n][1] = *(const bf16x8*)&Bb[rb_ + jx1];
        }
      }
      stage_q(qb + ph * 2);
      stage_q(qb + ph * 2 + 1);
      asm volatile("s_barrier" ::: "memory");
      asm volatile("s_waitcnt lgkmcnt(0)" ::: "memory");
      __builtin_amdgcn_sched_barrier(0);
      __builtin_amdgcn_s_setprio(1);
#pragma unroll
      for (int ks = 0; ks < 2; ks++)
#pragma unroll
        for (int mm = 0; mm < 2; mm++)
#pragma unroll
          for (int n = 0; n < 4; n++)
            acc[ph * 2 + mm][n] = __builtin_amdgcn_mfma_f32_16x16x32_bf16(
                af[mm][ks], bfr[n][ks], acc[ph * 2 + mm][n], 0, 0, 0);
      __builtin_amdgcn_s_setprio(0);
      if (ph == 3) {
        if (t < NT - 2)       asm volatile("s_waitcnt vmcnt(6)" ::: "memory");
        else if (t == NT - 2) asm volatile("s_waitcnt vmcnt(0)" ::: "memory");
      }
      asm volatile("s_barrier" ::: "memory");
    }
    qb += 8;
  }

  // epilogue
  const int rb0 = tm * 256 + wr * 128 + lg * 4;
  const int cb0 = tn * 256 + wc * 64 + lr;
#pragma unroll
  for (int m = 0; m < 8; m++) {
#pragma unroll
    for (int n = 0; n < 4; n++) {
      const int gj = cb0 + n * 16;
#pragma unroll
      for (int r = 0; r < 4; r++) {
        const int gi = rb0 + m * 16 + r;
        const float v = acc[m][n][r];
        if constexpr (MODE == 1) {          // h = relu(v + b1)
          float b = (gj < CENT_D) ? p.bias[gj] : 0.f;
          p.obf[(size_t)gi * p.ldo + gj] = f2bf(fmaxf(v + b, 0.f));
        } else {                            // MODE 2: out = exp(v + b2)
          float o = (gj < CENT_D) ? __expf(v + p.bias[gj]) : 0.f;
          p.obf[(size_t)gi * p.ldo + gj] = f2bf(o);
        }
      }
    }
  }
}

__global__ void cast_pad(const float* __restrict__ src, unsigned short* __restrict__ dst,
                         int R, int C, int Rp, int Cp) {
  int n = Rp * Cp;
  for (int i = blockIdx.x * blockDim.x + threadIdx.x; i < n; i += gridDim.x * blockDim.x) {
    int r = i / Cp, c = i - r * Cp;
    float v = (r < R && c < C) ? src[(size_t)r * C + c] : 0.f;
    dst[i] = f2bf(v);
  }
}

__global__ void rownorm(const float* __restrict__ src, float* __restrict__ dst,
                        int R, int C, int Rp) {
  int row = (int)((blockIdx.x * blockDim.x + threadIdx.x) >> 6);
  int l = threadIdx.x & 63;
  if (row >= Rp) return;
  float s = 0.f;
  if (row < R)
    for (int k = l; k < C; k += 64) { float v = src[(size_t)row * C + k]; s += v * v; }
#pragma unroll
  for (int off = 32; off > 0; off >>= 1) s += __shfl_down(s, off);
  if (l == 0) dst[row] = s;
}

__global__ void sigsq(const float* __restrict__ sg, float* __restrict__ out) {
  int j = threadIdx.x;
  out[j] = (j < HID_D) ? sg[j] * sg[j] : 0.f;
}

// d_out layout: [Ehat2 B*151][Rhat B*2000][Ehat2 B*151][Rhat B*2000][x B*151]
// part: 4 split-K slabs of Ehat partials, each B*151 f32
__global__ void finalize(float* __restrict__ dout, const unsigned short* __restrict__ outp,
                         const float* __restrict__ x, const float* __restrict__ part) {
  const int i = blockIdx.x;
  const size_t SL = (size_t)BDIM * IN_D;
  float* Eh = dout;
  float* Ra = dout + SL;
  float* Eb = dout + SL + (size_t)BDIM * CENT_D;
  float* Rb = Eb + SL;
  float* xo = Rb + (size_t)BDIM * CENT_D;
  const size_t ib = (size_t)i * IN_D;
  const float e0 = part[ib] + part[SL + ib] + part[2 * SL + ib] + part[3 * SL + ib];
  const float s = 1.f / e0;
  const int t = threadIdx.x;
  for (int j = t; j < IN_D; j += 256) {
    float v = (part[ib + j] + part[SL + ib + j] + part[2 * SL + ib + j] + part[3 * SL + ib + j]) * s;
    Eh[ib + j] = v;
    Eb[ib + j] = v;
    xo[ib + j] = x[ib + j];
  }
  const size_t ic = (size_t)i * CENT_D;
  for (int j = t; j < CENT_D; j += 256) {
    float rv = bf2f(outp[(size_t)i * CENTP + j]) * s;
    Ra[ic + j] = rv;
    Rb[ic + j] = rv;
  }
}

extern "C" void kernel_launch(void* const* d_in, const int* in_sizes, int n_in,
                              void* d_out, int out_size, void* d_ws, size_t ws_size,
                              hipStream_t stream) {
  (void)in_sizes; (void)n_in; (void)out_size; (void)ws_size;
  const float* x       = (const float*)d_in[0];
  const float* centres = (const float*)d_in[1];
  const float* sigmas  = (const float*)d_in[2];
  const float* w1      = (const float*)d_in[3];
  const float* b1      = (const float*)d_in[4];
  const float* w2      = (const float*)d_in[5];
  const float* b2      = (const float*)d_in[6];
  const float* kern    = (const float*)d_in[7];
  float* dout = (float*)d_out;

  char* ws = (char*)d_ws;
  size_t off = 0;
  auto alloc = [&](size_t bytes) {
    char* p = ws + off;
    off = (off + bytes + 255) & ~(size_t)255;
    return p;
  };
  unsigned short* x_bf  = (unsigned short*)alloc((size_t)BDIM * INP * 2);
  unsigned short* c_bf  = (unsigned short*)alloc((size_t)KERNR * INP * 2);
  unsigned short* w1p   = (unsigned short*)alloc((size_t)CENTP * HIDP * 2);
  unsigned short* w2p   = (unsigned short*)alloc((size_t)CENTP * CENTP * 2);
  unsigned short* kernp = (unsigned short*)alloc((size_t)KERNR * CENTP * 2);
  unsigned short* phip  = (unsigned short*)alloc((size_t)BDIM * HIDP * 2);
  unsigned short* outp  = (unsigned short*)alloc((size_t)BDIM * CENTP * 2);
  float* x2  = (float*)alloc((size_t)BDIM * 4);
  float* c2  = (float*)alloc((size_t)KERNR * 4);
  float* sg2 = (float*)alloc((size_t)KERNR * 4);
  float* eparts = (float*)alloc((size_t)4 * BDIM * IN_D * 4);  // split-K Ehat partials
  // h (bf16, B x 2048) lives in the Rhat_b output slot; consumed by GEMM2,
  // overwritten by finalize at the end.
  unsigned short* hp = (unsigned short*)(dout + (size_t)BDIM * (2 * IN_D + CENT_D));

  auto cgrid = [](long long n) { long long g = (n + 255) / 256; return (int)(g > 4096 ? 4096 : g); };
  cast_pad<<<cgrid((long long)BDIM * INP), 256, 0, stream>>>(x, x_bf, BDIM, IN_D, BDIM, INP);
  cast_pad<<<cgrid((long long)KERNR * INP), 256, 0, stream>>>(centres, c_bf, HID_D, IN_D, KERNR, INP);
  cast_pad<<<cgrid((long long)CENTP * HIDP), 256, 0, stream>>>(w1, w1p, CENT_D, HID_D, CENTP, HIDP);
  cast_pad<<<cgrid((long long)CENTP * CENTP), 256, 0, stream>>>(w2, w2p, CENT_D, CENT_D, CENTP, CENTP);
  cast_pad<<<cgrid((long long)KERNR * CENTP), 256, 0, stream>>>(kern, kernp, IN_D, CENT_D, KERNR, CENTP);
  rownorm<<<BDIM / 4, 256, 0, stream>>>(x, x2, BDIM, IN_D, BDIM);
  rownorm<<<KERNR / 4, 256, 0, stream>>>(centres, c2, HID_D, IN_D, KERNR);
  sigsq<<<1, 256, 0, stream>>>(sigmas, sg2);

  // GEMM0: phi (128^2 tile; N=256 -> only 2 col-tiles, 256 blocks)
  GArgs g0{}; g0.A = x_bf; g0.B = c_bf; g0.K = INP; g0.kspan = INP;
  g0.x2 = x2; g0.c2 = c2; g0.sg2 = sg2; g0.obf = phip; g0.ldo = HIDP;
  gemm_bt<0><<<dim3(BDIM / 128, HIDP / 128, 1), 256, 0, stream>>>(g0);

  // GEMM1: h = relu(phi @ w1^T + b1)  (256^2 8-phase, grid 64x8=512)
  GArgs g1{}; g1.A = phip; g1.B = w1p; g1.K = HIDP; g1.kspan = HIDP;
  g1.bias = b1; g1.obf = hp; g1.ldo = CENTP;
  gemm256<1><<<512, 512, 0, stream>>>(g1, 6);

  // GEMM2: out = exp(h @ w2^T + b2)  (dominant: 137 GFLOP)
  GArgs g2{}; g2.A = hp; g2.B = w2p; g2.K = CENTP; g2.kspan = CENTP;
  g2.bias = b2; g2.obf = outp; g2.ldo = CENTP;
  gemm256<2><<<512, 512, 0, stream>>>(g2, 6);

  // GEMM3: Ehat partials, split-K x4 (grid 128x2x4 = 1024 blocks)
  GArgs g3{}; g3.A = outp; g3.B = kernp; g3.K = CENTP; g3.kspan = CENTP / 4;
  g3.of = eparts;
  gemm_bt<3><<<dim3(BDIM / 128, KERNR / 128, 4), 256, 0, stream>>>(g3);

  finalize<<<BDIM, 256, 0, stream>>>(dout, outp, x, eparts);
}

// Round 3
// 362.224 us; speedup vs baseline: 1.0067x; 1.0067x over previous
//
#include <hip/hip_runtime.h>

#define BDIM 16384
#define IN_D 151
#define HID_D 200
#define CENT_D 2000

// padded dims
#define INP 192     // K of GEMM0
#define HIDP 256    // N of GEMM0, K of GEMM1
#define CENTP 2048  // N of GEMM1/2, K of GEMM2/3
#define KERNR 256   // padded rows for kern/centres

using bf16x8 = __attribute__((ext_vector_type(8))) short;
using f32x4  = __attribute__((ext_vector_type(4))) float;

__device__ __forceinline__ unsigned short f2bf(float f) {
  unsigned u = __builtin_bit_cast(unsigned, f);
  u += 0x7FFFu + ((u >> 16) & 1u);
  return (unsigned short)(u >> 16);
}
__device__ __forceinline__ float bf2f(unsigned short h) {
  unsigned u = ((unsigned)h) << 16;
  return __builtin_bit_cast(float, u);
}

typedef __attribute__((address_space(1))) const unsigned int guint;
typedef __attribute__((address_space(3))) unsigned int luint;
__device__ __forceinline__ void g2l16(const void* g, void* l) {
  __builtin_amdgcn_global_load_lds((guint*)g, (luint*)l, 16, 0, 0);
}

struct GArgs {
  const unsigned short* A;   // M x K bf16 row-major
  const unsigned short* B;   // N x K bf16 row-major
  int K;
  int kspan;                 // K-range per blockIdx.z
  const float* x2; const float* c2; const float* sg2;  // MODE 0
  const float* bias;                                    // MODE 1,2
  unsigned short* obf; int ldo;                         // MODE 0,1,2
  float* of;                                            // MODE 3 (per-z slab)
};

// ---------------------------------------------------------------------------
// 128x128 tile, BK=64, 4 waves, 2-barrier structure (GEMM0 / GEMM3 split-K).
// ---------------------------------------------------------------------------
template<int MODE>
__global__ __launch_bounds__(256) void gemm_bt(GArgs p) {
  __shared__ __align__(16) short As[128 * 64];
  __shared__ __align__(16) short Bs[128 * 64];
  const int tid  = threadIdx.x;
  const int lane = tid & 63;
  const int w    = tid >> 6;
  const int wr   = w >> 1, wc = w & 1;
  const int lr   = lane & 15;
  const int tm = blockIdx.x, tn = blockIdx.y;
  const int K = p.K;
  const int kz = blockIdx.z;
  const int kbeg = kz * p.kspan;
  f32x4 acc[4][4] = {};

  const unsigned short* Ag = p.A + (size_t)tm * 128 * K;
  const unsigned short* Bg = p.B + (size_t)tn * 128 * K;

  int rowc[4], colc[4], ldsc[4];
#pragma unroll
  for (int i = 0; i < 4; i++) {
    int cc = i * 256 + tid;
    rowc[i] = cc >> 3;
    colc[i] = ((cc & 7) ^ (rowc[i] & 7)) * 8;
    ldsc[i] = cc * 8;
  }

  for (int k0 = kbeg; k0 < kbeg + p.kspan; k0 += 64) {
    __syncthreads();
#pragma unroll
    for (int i = 0; i < 4; i++)
      g2l16(Ag + (size_t)rowc[i] * K + k0 + colc[i], &As[ldsc[i]]);
#pragma unroll
    for (int i = 0; i < 4; i++)
      g2l16(Bg + (size_t)rowc[i] * K + k0 + colc[i], &Bs[ldsc[i]]);
    __syncthreads();
#pragma unroll
    for (int ks = 0; ks < 2; ks++) {
      bf16x8 af[4], bfr[4];
#pragma unroll
      for (int m = 0; m < 4; m++) {
        int r = wr * 64 + m * 16 + lr;
        af[m] = *(const bf16x8*)&As[r * 64 + ((((ks << 2) + (lane >> 4)) ^ (r & 7)) << 3)];
      }
#pragma unroll
      for (int n = 0; n < 4; n++) {
        int r = wc * 64 + n * 16 + lr;
        bfr[n] = *(const bf16x8*)&Bs[r * 64 + ((((ks << 2) + (lane >> 4)) ^ (r & 7)) << 3)];
      }
#pragma unroll
      for (int m = 0; m < 4; m++)
#pragma unroll
        for (int n = 0; n < 4; n++)
          acc[m][n] = __builtin_amdgcn_mfma_f32_16x16x32_bf16(af[m], bfr[n], acc[m][n], 0, 0, 0);
    }
  }

  const int rb = tm * 128 + wr * 64 + (lane >> 4) * 4;
  const int cb = tn * 128 + wc * 64 + lr;
#pragma unroll
  for (int m = 0; m < 4; m++) {
#pragma unroll
    for (int n = 0; n < 4; n++) {
#pragma unroll
      for (int r = 0; r < 4; r++) {
        const int gi = rb + m * 16 + r;
        const int gj = cb + n * 16;
        const float v = acc[m][n][r];
        if constexpr (MODE == 0) {
          float ph = 0.f;
          if (gj < HID_D) {
            float d2 = fmaxf(p.x2[gi] + p.c2[gj] - 2.f * v, 0.f);
            ph = __expf(-d2 * p.sg2[gj]);
          }
          p.obf[(size_t)gi * p.ldo + gj] = f2bf(ph);
        } else if constexpr (MODE == 3) {
          float* of = p.of + (size_t)blockIdx.z * BDIM * IN_D;
          if (gj < IN_D) of[(size_t)gi * IN_D + gj] = v;
        }
      }
    }
  }
}

// ---------------------------------------------------------------------------
// 256x256 tile, BK=64, 8 waves (2Mx4N), 8-phase counted-vmcnt, 2-tile unroll.
// ALL buffer/subtile coordinates compile-time; stage = 1 add + g2l16.
// Per-tile stage mapping (tile u): ph0 -> u+1 A r1,r3; ph1 -> u+2 B r0,r1;
// ph2 -> u+2 B r2,r3; ph3 -> u+2 A r0,r2 + vmcnt(6).
// ---------------------------------------------------------------------------
#define WVN (void)0
#define WV6 asm volatile("s_waitcnt vmcnt(6)" ::: "memory")
#define WV0 asm volatile("s_waitcnt vmcnt(0)" ::: "memory")
#define STA(BUF, r, kk) g2l16(Ag + off[r] + (kk), &As[BUF][lof[r]])
#define STB(BUF, r, kk) g2l16(Bg + off[r] + (kk), &Bs[BUF][lof[r]])

#define PH_BODY(PH, BUF, WAITV, ...)                                          \
  {                                                                           \
    bf16x8 af[2][2];                                                          \
    _Pragma("unroll") for (int mm = 0; mm < 2; mm++) {                        \
      const int ra = (arow + ((PH) * 2 + mm) * 16) << 6;                      \
      af[mm][0] = *(const bf16x8*)&As[BUF][ra + jx0];                         \
      af[mm][1] = *(const bf16x8*)&As[BUF][ra + jx1];                         \
    }                                                                         \
    if ((PH) == 0) {                                                          \
      _Pragma("unroll") for (int n = 0; n < 4; n++) {                         \
        const int rbb = (brow + n * 16) << 6;                                 \
        bfr[n][0] = *(const bf16x8*)&Bs[BUF][rbb + jx0];                      \
        bfr[n][1] = *(const bf16x8*)&Bs[BUF][rbb + jx1];                      \
      }                                                                       \
    }                                                                         \
    __VA_ARGS__;                                                              \
    asm volatile("s_barrier" ::: "memory");                                   \
    asm volatile("s_waitcnt lgkmcnt(0)" ::: "memory");                        \
    __builtin_amdgcn_sched_barrier(0);                                        \
    __builtin_amdgcn_s_setprio(1);                                            \
    _Pragma("unroll") for (int ks = 0; ks < 2; ks++)                          \
      _Pragma("unroll") for (int mm = 0; mm < 2; mm++)                        \
        _Pragma("unroll") for (int n = 0; n < 4; n++)                         \
          acc[(PH) * 2 + mm][n] = __builtin_amdgcn_mfma_f32_16x16x32_bf16(    \
              af[mm][ks], bfr[n][ks], acc[(PH) * 2 + mm][n], 0, 0, 0);        \
    __builtin_amdgcn_s_setprio(0);                                            \
    WAITV;                                                                    \
    asm volatile("s_barrier" ::: "memory");                                   \
  }

#define TILE4(BUF, W3, S0C, S1C, S2C, S3C)   \
  {                                          \
    bf16x8 bfr[4][2];                        \
    PH_BODY(0, BUF, WVN, S0C);               \
    PH_BODY(1, BUF, WVN, S1C);               \
    PH_BODY(2, BUF, WVN, S2C);               \
    PH_BODY(3, BUF, W3, S3C);                \
  }

template<int MODE>
__global__ __launch_bounds__(512, 2) void gemm256(GArgs p, int nbxs) {
  __shared__ __align__(16) short As[2][256 * 64];
  __shared__ __align__(16) short Bs[2][256 * 64];
  const int tid  = threadIdx.x;
  const int lane = tid & 63;
  const int w    = tid >> 6;
  const int wr   = w >> 2;      // 0..1  (128-row slice)
  const int wc   = w & 3;       // 0..3  (64-col slice)
  const int lr   = lane & 15;
  const int lg   = lane >> 4;   // 0..3
  const int K    = p.K;
  const int NT   = K >> 6;      // assumed even, >= 4

  const int cpx = (int)gridDim.x >> 3;
  const int swz = ((int)blockIdx.x & 7) * cpx + ((int)blockIdx.x >> 3);
  const int tm = swz & ((1 << nbxs) - 1);
  const int tn = swz >> nbxs;

  const unsigned short* Ag = p.A + (size_t)tm * 256 * K;
  const unsigned short* Bg = p.B + (size_t)tn * 256 * K;

  f32x4 acc[8][4] = {};

  // per-thread staged-chunk offsets (identical geometry for A and B)
  size_t off[4]; int lof[4];
#pragma unroll
  for (int r = 0; r < 4; r++) {
    const int cc = (r << 9) + tid;
    const int row = cc >> 3, c8 = cc & 7;
    off[r] = (size_t)row * K + ((c8 ^ (row & 7)) << 3);
    lof[r] = cc << 3;
  }

  // prologue: tile0 all 8 rounds + tile1 rounds B0..B3, A0, A2
  {
#pragma unroll
    for (int r = 0; r < 4; r++) STB(0, r, 0);
#pragma unroll
    for (int r = 0; r < 4; r++) STA(0, r, 0);
    STB(1, 0, 64); STB(1, 1, 64); STB(1, 2, 64); STB(1, 3, 64);
    STA(1, 0, 64); STA(1, 2, 64);
    WV6;
    asm volatile("s_barrier" ::: "memory");
  }

  const int jx0 = ((0 + lg) ^ (lr & 7)) << 3;
  const int jx1 = ((4 + lg) ^ (lr & 7)) << 3;
  const int arow = wr * 128 + lr;
  const int brow = wc * 64 + lr;

  // steady state: 2 tiles per iteration, compile-time buffers
  for (int t = 0; t < NT - 2; t += 2) {
    const int k1 = (t + 1) << 6, k2 = (t + 2) << 6, k3 = (t + 3) << 6;
    TILE4(0, WV6,
          STA(1, 1, k1); STA(1, 3, k1),
          STB(0, 0, k2); STB(0, 1, k2),
          STB(0, 2, k2); STB(0, 3, k2),
          STA(0, 0, k2); STA(0, 2, k2));
    TILE4(1, WV6,
          STA(0, 1, k2); STA(0, 3, k2),
          STB(1, 0, k3); STB(1, 1, k3),
          STB(1, 2, k3); STB(1, 3, k3),
          STA(1, 0, k3); STA(1, 2, k3));
  }
  // epilogue: tiles NT-2 (buf0) and NT-1 (buf1)
  {
    const int kl = (NT - 1) << 6;
    TILE4(0, WV0,
          STA(1, 1, kl); STA(1, 3, kl),
          WVN, WVN, WVN);
    TILE4(1, WVN, WVN, WVN, WVN, WVN);
  }

  const int rb0 = tm * 256 + wr * 128 + lg * 4;
  const int cb0 = tn * 256 + wc * 64 + lr;
#pragma unroll
  for (int m = 0; m < 8; m++) {
#pragma unroll
    for (int n = 0; n < 4; n++) {
      const int gj = cb0 + n * 16;
#pragma unroll
      for (int r = 0; r < 4; r++) {
        const int gi = rb0 + m * 16 + r;
        const float v = acc[m][n][r];
        if constexpr (MODE == 1) {          // h = relu(v + b1)
          float b = (gj < CENT_D) ? p.bias[gj] : 0.f;
          p.obf[(size_t)gi * p.ldo + gj] = f2bf(fmaxf(v + b, 0.f));
        } else {                            // MODE 2: out = exp(v + b2)
          float o = (gj < CENT_D) ? __expf(v + p.bias[gj]) : 0.f;
          p.obf[(size_t)gi * p.ldo + gj] = f2bf(o);
        }
      }
    }
  }
}

__global__ void cast_pad(const float* __restrict__ src, unsigned short* __restrict__ dst,
                         int R, int C, int Rp, int Cp) {
  int n = Rp * Cp;
  for (int i = blockIdx.x * blockDim.x + threadIdx.x; i < n; i += gridDim.x * blockDim.x) {
    int r = i / Cp, c = i - r * Cp;
    float v = (r < R && c < C) ? src[(size_t)r * C + c] : 0.f;
    dst[i] = f2bf(v);
  }
}

__global__ void rownorm(const float* __restrict__ src, float* __restrict__ dst,
                        int R, int C, int Rp) {
  int row = (int)((blockIdx.x * blockDim.x + threadIdx.x) >> 6);
  int l = threadIdx.x & 63;
  if (row >= Rp) return;
  float s = 0.f;
  if (row < R)
    for (int k = l; k < C; k += 64) { float v = src[(size_t)row * C + k]; s += v * v; }
#pragma unroll
  for (int off = 32; off > 0; off >>= 1) s += __shfl_down(s, off);
  if (l == 0) dst[row] = s;
}

__global__ void sigsq(const float* __restrict__ sg, float* __restrict__ out) {
  int j = threadIdx.x;
  out[j] = (j < HID_D) ? sg[j] * sg[j] : 0.f;
}

// d_out layout: [Ehat2 B*151][Rhat B*2000][Ehat2 B*151][Rhat B*2000][x B*151]
__global__ void finalize(float* __restrict__ dout, const unsigned short* __restrict__ outp,
                         const float* __restrict__ x, const float* __restrict__ part) {
  const int i = blockIdx.x;
  const size_t SL = (size_t)BDIM * IN_D;
  float* Eh = dout;
  float* Ra = dout + SL;
  float* Eb = dout + SL + (size_t)BDIM * CENT_D;
  float* Rb = Eb + SL;
  float* xo = Rb + (size_t)BDIM * CENT_D;
  const size_t ib = (size_t)i * IN_D;
  const float e0 = part[ib] + part[SL + ib] + part[2 * SL + ib] + part[3 * SL + ib];
  const float s = 1.f / e0;
  const int t = threadIdx.x;
  for (int j = t; j < IN_D; j += 256) {
    float v = (part[ib + j] + part[SL + ib + j] + part[2 * SL + ib + j] + part[3 * SL + ib + j]) * s;
    Eh[ib + j] = v;
    Eb[ib + j] = v;
    xo[ib + j] = x[ib + j];
  }
  const size_t ic = (size_t)i * CENT_D;
  for (int j = t; j < CENT_D; j += 256) {
    float rv = bf2f(outp[(size_t)i * CENTP + j]) * s;
    Ra[ic + j] = rv;
    Rb[ic + j] = rv;
  }
}

extern "C" void kernel_launch(void* const* d_in, const int* in_sizes, int n_in,
                              void* d_out, int out_size, void* d_ws, size_t ws_size,
                              hipStream_t stream) {
  (void)in_sizes; (void)n_in; (void)out_size; (void)ws_size;
  const float* x       = (const float*)d_in[0];
  const float* centres = (const float*)d_in[1];
  const float* sigmas  = (const float*)d_in[2];
  const float* w1      = (const float*)d_in[3];
  const float* b1      = (const float*)d_in[4];
  const float* w2      = (const float*)d_in[5];
  const float* b2      = (const float*)d_in[6];
  const float* kern    = (const float*)d_in[7];
  float* dout = (float*)d_out;

  char* ws = (char*)d_ws;
  size_t off = 0;
  auto alloc = [&](size_t bytes) {
    char* p = ws + off;
    off = (off + bytes + 255) & ~(size_t)255;
    return p;
  };
  unsigned short* x_bf  = (unsigned short*)alloc((size_t)BDIM * INP * 2);
  unsigned short* c_bf  = (unsigned short*)alloc((size_t)KERNR * INP * 2);
  unsigned short* w1p   = (unsigned short*)alloc((size_t)CENTP * HIDP * 2);
  unsigned short* w2p   = (unsigned short*)alloc((size_t)CENTP * CENTP * 2);
  unsigned short* kernp = (unsigned short*)alloc((size_t)KERNR * CENTP * 2);
  unsigned short* phip  = (unsigned short*)alloc((size_t)BDIM * HIDP * 2);
  unsigned short* outp  = (unsigned short*)alloc((size_t)BDIM * CENTP * 2);
  float* x2  = (float*)alloc((size_t)BDIM * 4);
  float* c2  = (float*)alloc((size_t)KERNR * 4);
  float* sg2 = (float*)alloc((size_t)KERNR * 4);
  float* eparts = (float*)alloc((size_t)4 * BDIM * IN_D * 4);
  unsigned short* hp = (unsigned short*)(dout + (size_t)BDIM * (2 * IN_D + CENT_D));

  auto cgrid = [](long long n) { long long g = (n + 255) / 256; return (int)(g > 4096 ? 4096 : g); };
  cast_pad<<<cgrid((long long)BDIM * INP), 256, 0, stream>>>(x, x_bf, BDIM, IN_D, BDIM, INP);
  cast_pad<<<cgrid((long long)KERNR * INP), 256, 0, stream>>>(centres, c_bf, HID_D, IN_D, KERNR, INP);
  cast_pad<<<cgrid((long long)CENTP * HIDP), 256, 0, stream>>>(w1, w1p, CENT_D, HID_D, CENTP, HIDP);
  cast_pad<<<cgrid((long long)CENTP * CENTP), 256, 0, stream>>>(w2, w2p, CENT_D, CENT_D, CENTP, CENTP);
  cast_pad<<<cgrid((long long)KERNR * CENTP), 256, 0, stream>>>(kern, kernp, IN_D, CENT_D, KERNR, CENTP);
  rownorm<<<BDIM / 4, 256, 0, stream>>>(x, x2, BDIM, IN_D, BDIM);
  rownorm<<<KERNR / 4, 256, 0, stream>>>(centres, c2, HID_D, IN_D, KERNR);
  sigsq<<<1, 256, 0, stream>>>(sigmas, sg2);

  GArgs g0{}; g0.A = x_bf; g0.B = c_bf; g0.K = INP; g0.kspan = INP;
  g0.x2 = x2; g0.c2 = c2; g0.sg2 = sg2; g0.obf = phip; g0.ldo = HIDP;
  gemm_bt<0><<<dim3(BDIM / 128, HIDP / 128, 1), 256, 0, stream>>>(g0);

  GArgs g1{}; g1.A = phip; g1.B = w1p; g1.K = HIDP; g1.kspan = HIDP;
  g1.bias = b1; g1.obf = hp; g1.ldo = CENTP;
  gemm256<1><<<512, 512, 0, stream>>>(g1, 6);

  GArgs g2{}; g2.A = hp; g2.B = w2p; g2.K = CENTP; g2.kspan = CENTP;
  g2.bias = b2; g2.obf = outp; g2.ldo = CENTP;
  gemm256<2><<<512, 512, 0, stream>>>(g2, 6);

  GArgs g3{}; g3.A = outp; g3.B = kernp; g3.K = CENTP; g3.kspan = CENTP / 4;
  g3.of = eparts;
  gemm_bt<3><<<dim3(BDIM / 128, KERNR / 128, 4), 256, 0, stream>>>(g3);

  finalize<<<BDIM, 256, 0, stream>>>(dout, outp, x, eparts);
}

// Round 4
// 341.289 us; speedup vs baseline: 1.0685x; 1.0613x over previous
//
#include <hip/hip_runtime.h>

#define BDIM 16384
#define IN_D 151
#define HID_D 200
#define CENT_D 2000

// padded dims
#define INP 192     // K of GEMM0
#define HIDP 256    // N of GEMM0, K of GEMM1
#define CENTP 2048  // N of GEMM1/2, K of GEMM2/3
#define KERNR 256   // padded rows for kern/centres

using bf16x8 = __attribute__((ext_vector_type(8))) short;
using f32x4  = __attribute__((ext_vector_type(4))) float;
using f4     = __attribute__((ext_vector_type(4))) float;
using us4    = __attribute__((ext_vector_type(4))) unsigned short;
using us8    = __attribute__((ext_vector_type(8))) unsigned short;

__device__ __forceinline__ unsigned short f2bf(float f) {
  unsigned u = __builtin_bit_cast(unsigned, f);
  u += 0x7FFFu + ((u >> 16) & 1u);
  return (unsigned short)(u >> 16);
}
__device__ __forceinline__ float bf2f(unsigned short h) {
  unsigned u = ((unsigned)h) << 16;
  return __builtin_bit_cast(float, u);
}

typedef __attribute__((address_space(1))) const unsigned int guint;
typedef __attribute__((address_space(3))) unsigned int luint;
__device__ __forceinline__ void g2l16(const void* g, void* l) {
  __builtin_amdgcn_global_load_lds((guint*)g, (luint*)l, 16, 0, 0);
}

struct GArgs {
  const unsigned short* A;   // M x K bf16 row-major
  const unsigned short* B;   // N x K bf16 row-major
  int K;
  int kspan;                 // K-range per blockIdx.z
  const float* x2; const float* c2; const float* sg2;  // MODE 0
  const float* bias;                                    // MODE 1,2
  unsigned short* obf; int ldo;                         // MODE 0,1,2
  float* of;                                            // MODE 3 (per-z slab)
};

// ---------------------------------------------------------------------------
// 128x128 tile, BK=64, 4 waves, 2-barrier structure (proven ~900 TF class).
// ---------------------------------------------------------------------------
template<int MODE>
__global__ __launch_bounds__(256) void gemm_bt(GArgs p) {
  __shared__ __align__(16) short As[128 * 64];
  __shared__ __align__(16) short Bs[128 * 64];
  const int tid  = threadIdx.x;
  const int lane = tid & 63;
  const int w    = tid >> 6;
  const int wr   = w >> 1, wc = w & 1;
  const int lr   = lane & 15;
  const int tm = blockIdx.x, tn = blockIdx.y;
  const int K = p.K;
  const int kbeg = blockIdx.z * p.kspan;
  f32x4 acc[4][4] = {};

  const unsigned short* Ag = p.A + (size_t)tm * 128 * K;
  const unsigned short* Bg = p.B + (size_t)tn * 128 * K;

  int rowc[4], colc[4], ldsc[4];
#pragma unroll
  for (int i = 0; i < 4; i++) {
    int cc = i * 256 + tid;
    rowc[i] = cc >> 3;
    colc[i] = ((cc & 7) ^ (rowc[i] & 7)) * 8;
    ldsc[i] = cc * 8;
  }

  for (int k0 = kbeg; k0 < kbeg + p.kspan; k0 += 64) {
    __syncthreads();
#pragma unroll
    for (int i = 0; i < 4; i++)
      g2l16(Ag + (size_t)rowc[i] * K + k0 + colc[i], &As[ldsc[i]]);
#pragma unroll
    for (int i = 0; i < 4; i++)
      g2l16(Bg + (size_t)rowc[i] * K + k0 + colc[i], &Bs[ldsc[i]]);
    __syncthreads();
#pragma unroll
    for (int ks = 0; ks < 2; ks++) {
      bf16x8 af[4], bfr[4];
#pragma unroll
      for (int m = 0; m < 4; m++) {
        int r = wr * 64 + m * 16 + lr;
        af[m] = *(const bf16x8*)&As[r * 64 + ((((ks << 2) + (lane >> 4)) ^ (r & 7)) << 3)];
      }
#pragma unroll
      for (int n = 0; n < 4; n++) {
        int r = wc * 64 + n * 16 + lr;
        bfr[n] = *(const bf16x8*)&Bs[r * 64 + ((((ks << 2) + (lane >> 4)) ^ (r & 7)) << 3)];
      }
#pragma unroll
      for (int m = 0; m < 4; m++)
#pragma unroll
        for (int n = 0; n < 4; n++)
          acc[m][n] = __builtin_amdgcn_mfma_f32_16x16x32_bf16(af[m], bfr[n], acc[m][n], 0, 0, 0);
    }
  }

  const int rb = tm * 128 + wr * 64 + (lane >> 4) * 4;
  const int cb = tn * 128 + wc * 64 + lr;
#pragma unroll
  for (int m = 0; m < 4; m++) {
#pragma unroll
    for (int n = 0; n < 4; n++) {
#pragma unroll
      for (int r = 0; r < 4; r++) {
        const int gi = rb + m * 16 + r;
        const int gj = cb + n * 16;
        const float v = acc[m][n][r];
        if constexpr (MODE == 0) {          // phi = exp(-max(x2+c2-2*dot,0)*sig^2)
          float ph = 0.f;
          if (gj < HID_D) {
            float d2 = fmaxf(p.x2[gi] + p.c2[gj] - 2.f * v, 0.f);
            ph = __expf(-d2 * p.sg2[gj]);
          }
          p.obf[(size_t)gi * p.ldo + gj] = f2bf(ph);
        } else if constexpr (MODE == 1) {   // h = relu(v + b1)
          float b = (gj < CENT_D) ? p.bias[gj] : 0.f;
          p.obf[(size_t)gi * p.ldo + gj] = f2bf(fmaxf(v + b, 0.f));
        } else if constexpr (MODE == 2) {   // out = exp(v + b2)
          float o = (gj < CENT_D) ? __expf(v + p.bias[gj]) : 0.f;
          p.obf[(size_t)gi * p.ldo + gj] = f2bf(o);
        } else {                            // MODE 3: Ehat partial (per-z slab)
          float* of = p.of + (size_t)blockIdx.z * BDIM * IN_D;
          if (gj < IN_D) of[(size_t)gi * IN_D + gj] = v;
        }
      }
    }
  }
}

// ---------------------------------------------------------------------------
// Fused cast+pad of all 5 weight/input tensors. One chunk = 4 dst bf16.
// Segment chunk boundaries (exact): x 786432 | cen 798720 | w1 929792 |
// w2 1978368 | kern 2109440.  Total blocks = 2109440/256 = 8240.
// ---------------------------------------------------------------------------
__global__ __launch_bounds__(256) void prep_cast(
    const float* __restrict__ x, const float* __restrict__ cen,
    const float* __restrict__ w1, const float* __restrict__ w2,
    const float* __restrict__ kern,
    unsigned short* __restrict__ x_bf, unsigned short* __restrict__ c_bf,
    unsigned short* __restrict__ w1p, unsigned short* __restrict__ w2p,
    unsigned short* __restrict__ kernp) {
  const int c = blockIdx.x * 256 + threadIdx.x;
  const float* src; unsigned short* dst; int R, C, cpq, local, vec;
  if (c < 786432)       { src = x;    dst = x_bf;  R = 16384; C = 151;  cpq = 48;  local = c;           vec = 0; }
  else if (c < 798720)  { src = cen;  dst = c_bf;  R = 200;   C = 151;  cpq = 48;  local = c - 786432;  vec = 0; }
  else if (c < 929792)  { src = w1;   dst = w1p;   R = 2000;  C = 200;  cpq = 64;  local = c - 798720;  vec = 1; }
  else if (c < 1978368) { src = w2;   dst = w2p;   R = 2000;  C = 2000; cpq = 512; local = c - 929792;  vec = 1; }
  else                  { src = kern; dst = kernp; R = 151;   C = 2000; cpq = 512; local = c - 1978368; vec = 1; }
  const int r  = local / cpq;
  const int c4 = (local - r * cpq) << 2;
  us4 o;
  if (vec && r < R && c4 + 3 < C) {
    f4 v = *(const f4*)&src[(size_t)r * C + c4];   // aligned: C%4==0, c4%4==0
    o[0] = f2bf(v[0]); o[1] = f2bf(v[1]); o[2] = f2bf(v[2]); o[3] = f2bf(v[3]);
  } else {
#pragma unroll
    for (int k = 0; k < 4; k++) {
      float v = (r < R && c4 + k < C) ? src[(size_t)r * C + c4 + k] : 0.f;
      o[k] = f2bf(v);
    }
  }
  *(us4*)&dst[(size_t)local * 4] = o;
}

// ---------------------------------------------------------------------------
// Fused rownorm(x) + rownorm(centres) + sigmas^2.  4161 blocks:
// [0,4096) x rows, [4096,4160) centre rows (padded to 256), 4160 sigsq.
// ---------------------------------------------------------------------------
__global__ __launch_bounds__(256) void prep_misc(
    const float* __restrict__ x, const float* __restrict__ cen,
    const float* __restrict__ sg,
    float* __restrict__ x2, float* __restrict__ c2, float* __restrict__ sg2) {
  const int b = blockIdx.x;
  if (b == 4160) {
    int j = threadIdx.x;
    sg2[j] = (j < HID_D) ? sg[j] * sg[j] : 0.f;
    return;
  }
  const float* src; float* dst; int R, base;
  if (b < 4096) { src = x;   dst = x2; R = BDIM;  base = b * 4; }
  else          { src = cen; dst = c2; R = HID_D; base = (b - 4096) * 4; }
  const int row = base + (threadIdx.x >> 6);
  const int l = threadIdx.x & 63;
  float s = 0.f;
  if (row < R)
    for (int k = l; k < IN_D; k += 64) { float v = src[(size_t)row * IN_D + k]; s += v * v; }
#pragma unroll
  for (int off = 32; off > 0; off >>= 1) s += __shfl_down(s, off);
  if (l == 0) dst[row] = s;
}

// ---------------------------------------------------------------------------
// d_out layout: [Ehat2 B*151][Rhat B*2000][Ehat2 B*151][Rhat B*2000][x B*151]
// Vectorized: outp read as ushort8 (16B), Rhat written as float4.
// ---------------------------------------------------------------------------
__global__ __launch_bounds__(256) void finalize(
    float* __restrict__ dout, const unsigned short* __restrict__ outp,
    const float* __restrict__ x, const float* __restrict__ part) {
  const int i = blockIdx.x;
  const size_t SL = (size_t)BDIM * IN_D;
  float* Eh = dout;
  float* Ra = dout + SL;
  float* Eb = dout + SL + (size_t)BDIM * CENT_D;
  float* Rb = Eb + SL;
  float* xo = Rb + (size_t)BDIM * CENT_D;
  const size_t ib = (size_t)i * IN_D;
  const float e0 = part[ib] + part[SL + ib] + part[2 * SL + ib] + part[3 * SL + ib];
  const float s = 1.f / e0;
  const int t = threadIdx.x;
  if (t < IN_D) {
    float v = (part[ib + t] + part[SL + ib + t] + part[2 * SL + ib + t] + part[3 * SL + ib + t]) * s;
    Eh[ib + t] = v;
    Eb[ib + t] = v;
    xo[ib + t] = x[ib + t];
  }
  if (t < 250) {  // 250 * 8 = 2000
    const us8 u = *(const us8*)&outp[(size_t)i * CENTP + t * 8];
    f4 a, b;
#pragma unroll
    for (int k = 0; k < 4; k++) a[k] = bf2f(u[k]) * s;
#pragma unroll
    for (int k = 0; k < 4; k++) b[k] = bf2f(u[4 + k]) * s;
    const size_t o = (size_t)i * CENT_D + t * 8;
    *(f4*)&Ra[o] = a; *(f4*)&Ra[o + 4] = b;
    *(f4*)&Rb[o] = a; *(f4*)&Rb[o + 4] = b;
  }
}

extern "C" void kernel_launch(void* const* d_in, const int* in_sizes, int n_in,
                              void* d_out, int out_size, void* d_ws, size_t ws_size,
                              hipStream_t stream) {
  (void)in_sizes; (void)n_in; (void)out_size; (void)ws_size;
  const float* x       = (const float*)d_in[0];
  const float* centres = (const float*)d_in[1];
  const float* sigmas  = (const float*)d_in[2];
  const float* w1      = (const float*)d_in[3];
  const float* b1      = (const float*)d_in[4];
  const float* w2      = (const float*)d_in[5];
  const float* b2      = (const float*)d_in[6];
  const float* kern    = (const float*)d_in[7];
  float* dout = (float*)d_out;

  char* ws = (char*)d_ws;
  size_t off = 0;
  auto alloc = [&](size_t bytes) {
    char* p = ws + off;
    off = (off + bytes + 255) & ~(size_t)255;
    return p;
  };
  unsigned short* x_bf  = (unsigned short*)alloc((size_t)BDIM * INP * 2);
  unsigned short* c_bf  = (unsigned short*)alloc((size_t)KERNR * INP * 2);
  unsigned short* w1p   = (unsigned short*)alloc((size_t)CENTP * HIDP * 2);
  unsigned short* w2p   = (unsigned short*)alloc((size_t)CENTP * CENTP * 2);
  unsigned short* kernp = (unsigned short*)alloc((size_t)KERNR * CENTP * 2);
  unsigned short* phip  = (unsigned short*)alloc((size_t)BDIM * HIDP * 2);
  unsigned short* outp  = (unsigned short*)alloc((size_t)BDIM * CENTP * 2);
  float* x2  = (float*)alloc((size_t)BDIM * 4);
  float* c2  = (float*)alloc((size_t)KERNR * 4);
  float* sg2 = (float*)alloc((size_t)KERNR * 4);
  float* eparts = (float*)alloc((size_t)4 * BDIM * IN_D * 4);
  // h (bf16, B x 2048) lives in the Rhat_b output slot; consumed by GEMM2,
  // overwritten by finalize at the end (stream-sequential, safe).
  unsigned short* hp = (unsigned short*)(dout + (size_t)BDIM * (2 * IN_D + CENT_D));

  prep_cast<<<8240, 256, 0, stream>>>(x, centres, w1, w2, kern,
                                      x_bf, c_bf, w1p, w2p, kernp);
  prep_misc<<<4161, 256, 0, stream>>>(x, centres, sigmas, x2, c2, sg2);

  // GEMM0: phi  (M=16384, N=256, K=192)
  GArgs g0{}; g0.A = x_bf; g0.B = c_bf; g0.K = INP; g0.kspan = INP;
  g0.x2 = x2; g0.c2 = c2; g0.sg2 = sg2; g0.obf = phip; g0.ldo = HIDP;
  gemm_bt<0><<<dim3(BDIM / 128, HIDP / 128, 1), 256, 0, stream>>>(g0);

  // GEMM1: h = relu(phi @ w1^T + b1)  (M=16384, N=2048, K=256)
  GArgs g1{}; g1.A = phip; g1.B = w1p; g1.K = HIDP; g1.kspan = HIDP;
  g1.bias = b1; g1.obf = hp; g1.ldo = CENTP;
  gemm_bt<1><<<dim3(BDIM / 128, CENTP / 128, 1), 256, 0, stream>>>(g1);

  // GEMM2: out = exp(h @ w2^T + b2)  (M=16384, N=2048, K=2048 — dominant)
  GArgs g2{}; g2.A = hp; g2.B = w2p; g2.K = CENTP; g2.kspan = CENTP;
  g2.bias = b2; g2.obf = outp; g2.ldo = CENTP;
  gemm_bt<2><<<dim3(BDIM / 128, CENTP / 128, 1), 256, 0, stream>>>(g2);

  // GEMM3: Ehat partials, split-K x4 (1024 blocks)
  GArgs g3{}; g3.A = outp; g3.B = kernp; g3.K = CENTP; g3.kspan = CENTP / 4;
  g3.of = eparts;
  gemm_bt<3><<<dim3(BDIM / 128, KERNR / 128, 4), 256, 0, stream>>>(g3);

  finalize<<<BDIM, 256, 0, stream>>>(dout, outp, x, eparts);
}

// Round 5
// 280.260 us; speedup vs baseline: 1.3012x; 1.2178x over previous
//
#include <hip/hip_runtime.h>

#define BDIM 16384
#define IN_D 151
#define HID_D 200
#define CENT_D 2000

// padded dims
#define INP 192     // K of GEMM0
#define HIDP 256    // N of GEMM0, K of GEMM1
#define CENTP 2048  // N of GEMM1/2, K of GEMM2/3
#define KERNR 256   // padded rows for kern/centres

using bf16x8 = __attribute__((ext_vector_type(8))) short;
using f32x4  = __attribute__((ext_vector_type(4))) float;
using f4     = __attribute__((ext_vector_type(4))) float;
using us4    = __attribute__((ext_vector_type(4))) unsigned short;
using us8    = __attribute__((ext_vector_type(8))) unsigned short;
using i32x4  = __attribute__((ext_vector_type(4))) int;
using i32x8  = __attribute__((ext_vector_type(8))) int;

__device__ __forceinline__ unsigned short f2bf(float f) {
  unsigned u = __builtin_bit_cast(unsigned, f);
  u += 0x7FFFu + ((u >> 16) & 1u);
  return (unsigned short)(u >> 16);
}
__device__ __forceinline__ float bf2f(unsigned short h) {
  unsigned u = ((unsigned)h) << 16;
  return __builtin_bit_cast(float, u);
}
__device__ __forceinline__ unsigned char f2fp8(float f) {
  return (unsigned char)(__builtin_amdgcn_cvt_pk_fp8_f32(f, f, 0, false) & 0xFF);
}

typedef __attribute__((address_space(1))) const unsigned int guint;
typedef __attribute__((address_space(3))) unsigned int luint;
__device__ __forceinline__ void g2l16(const void* g, void* l) {
  __builtin_amdgcn_global_load_lds((guint*)g, (luint*)l, 16, 0, 0);
}

struct GArgs {
  const unsigned short* A;   // M x K bf16 row-major
  const unsigned short* B;   // N x K bf16 row-major
  int K;
  int kspan;                 // K-range per blockIdx.z
  const float* x2; const float* c2; const float* sg2;  // MODE 0
  const float* bias;                                    // MODE 1
  unsigned short* obf; int ldo;                         // MODE 0
  unsigned char* o8;                                    // MODE 1 (fp8 h)
  float* of;                                            // MODE 3 (per-z slab)
};

// ---------------------------------------------------------------------------
// bf16 128x128 tile, BK=64, 4 waves, 2-barrier structure (GEMM0/1/3).
// ---------------------------------------------------------------------------
template<int MODE>
__global__ __launch_bounds__(256) void gemm_bt(GArgs p) {
  __shared__ __align__(16) short As[128 * 64];
  __shared__ __align__(16) short Bs[128 * 64];
  const int tid  = threadIdx.x;
  const int lane = tid & 63;
  const int w    = tid >> 6;
  const int wr   = w >> 1, wc = w & 1;
  const int lr   = lane & 15;
  const int tm = blockIdx.x, tn = blockIdx.y;
  const int K = p.K;
  const int kbeg = blockIdx.z * p.kspan;
  f32x4 acc[4][4] = {};

  const unsigned short* Ag = p.A + (size_t)tm * 128 * K;
  const unsigned short* Bg = p.B + (size_t)tn * 128 * K;

  int rowc[4], colc[4], ldsc[4];
#pragma unroll
  for (int i = 0; i < 4; i++) {
    int cc = i * 256 + tid;
    rowc[i] = cc >> 3;
    colc[i] = ((cc & 7) ^ (rowc[i] & 7)) * 8;
    ldsc[i] = cc * 8;
  }

  for (int k0 = kbeg; k0 < kbeg + p.kspan; k0 += 64) {
    __syncthreads();
#pragma unroll
    for (int i = 0; i < 4; i++)
      g2l16(Ag + (size_t)rowc[i] * K + k0 + colc[i], &As[ldsc[i]]);
#pragma unroll
    for (int i = 0; i < 4; i++)
      g2l16(Bg + (size_t)rowc[i] * K + k0 + colc[i], &Bs[ldsc[i]]);
    __syncthreads();
#pragma unroll
    for (int ks = 0; ks < 2; ks++) {
      bf16x8 af[4], bfr[4];
#pragma unroll
      for (int m = 0; m < 4; m++) {
        int r = wr * 64 + m * 16 + lr;
        af[m] = *(const bf16x8*)&As[r * 64 + ((((ks << 2) + (lane >> 4)) ^ (r & 7)) << 3)];
      }
#pragma unroll
      for (int n = 0; n < 4; n++) {
        int r = wc * 64 + n * 16 + lr;
        bfr[n] = *(const bf16x8*)&Bs[r * 64 + ((((ks << 2) + (lane >> 4)) ^ (r & 7)) << 3)];
      }
#pragma unroll
      for (int m = 0; m < 4; m++)
#pragma unroll
        for (int n = 0; n < 4; n++)
          acc[m][n] = __builtin_amdgcn_mfma_f32_16x16x32_bf16(af[m], bfr[n], acc[m][n], 0, 0, 0);
    }
  }

  const int rb = tm * 128 + wr * 64 + (lane >> 4) * 4;
  const int cb = tn * 128 + wc * 64 + lr;
#pragma unroll
  for (int m = 0; m < 4; m++) {
#pragma unroll
    for (int n = 0; n < 4; n++) {
#pragma unroll
      for (int r = 0; r < 4; r++) {
        const int gi = rb + m * 16 + r;
        const int gj = cb + n * 16;
        const float v = acc[m][n][r];
        if constexpr (MODE == 0) {          // phi = exp(-max(x2+c2-2*dot,0)*sig^2)
          float ph = 0.f;
          if (gj < HID_D) {
            float d2 = fmaxf(p.x2[gi] + p.c2[gj] - 2.f * v, 0.f);
            ph = __expf(-d2 * p.sg2[gj]);
          }
          p.obf[(size_t)gi * p.ldo + gj] = f2bf(ph);
        } else if constexpr (MODE == 1) {   // h = relu(v + b1) -> fp8 e4m3
          float b = (gj < CENT_D) ? p.bias[gj] : 0.f;
          p.o8[(size_t)gi * p.ldo + gj] = f2fp8(fmaxf(v + b, 0.f));
        } else {                            // MODE 3: Ehat partial (per-z slab)
          float* of = p.of + (size_t)blockIdx.z * BDIM * IN_D;
          if (gj < IN_D) of[(size_t)gi * IN_D + gj] = v;
        }
      }
    }
  }
}

// ---------------------------------------------------------------------------
// MX-fp8 128x128 tile, BK=128 (=128B/row, byte-identical staging geometry to
// the bf16 BK=64 kernel), identity E8M0 scales (127), 16 scale-MFMAs/K-tile.
// out = exp(acc * 2^-8 + b2)  (w2 was pre-scaled by 2^8).
// ---------------------------------------------------------------------------
struct G8Args {
  const unsigned char* A;   // M x K fp8 row-major (h)
  const unsigned char* B;   // N x K fp8 row-major (w2 * 256)
  int K;
  const float* bias;
  unsigned short* obf; int ldo;
};

__global__ __launch_bounds__(256) void gemm_fp8(G8Args p) {
  __shared__ __align__(16) unsigned char As[128 * 128];
  __shared__ __align__(16) unsigned char Bs[128 * 128];
  const int tid  = threadIdx.x;
  const int lane = tid & 63;
  const int w    = tid >> 6;
  const int wr   = w >> 1, wc = w & 1;
  const int lr   = lane & 15;
  const int g    = lane >> 4;       // k-group 0..3 (32 fp8 elems each)
  const int tm = blockIdx.x, tn = blockIdx.y;
  const int K = p.K;
  f32x4 acc[4][4] = {};

  const unsigned char* Ag = p.A + (size_t)tm * 128 * K;
  const unsigned char* Bg = p.B + (size_t)tn * 128 * K;

  int rowc[4], colb[4], ldsb[4];
#pragma unroll
  for (int i = 0; i < 4; i++) {
    int cc = i * 256 + tid;          // 16B chunk id; 8 chunks per 128B row
    rowc[i] = cc >> 3;
    colb[i] = ((cc & 7) ^ (rowc[i] & 7)) << 4;   // pre-swizzled source byte col
    ldsb[i] = cc << 4;               // linear LDS dest (bytes)
  }

  for (int k0 = 0; k0 < K; k0 += 128) {
    __syncthreads();
#pragma unroll
    for (int i = 0; i < 4; i++)
      g2l16(Ag + (size_t)rowc[i] * K + k0 + colb[i], &As[ldsb[i]]);
#pragma unroll
    for (int i = 0; i < 4; i++)
      g2l16(Bg + (size_t)rowc[i] * K + k0 + colb[i], &Bs[ldsb[i]]);
    __syncthreads();

    i32x8 bfr[4];
#pragma unroll
    for (int n = 0; n < 4; n++) {
      const int r = wc * 64 + n * 16 + lr;
      const int rb_ = r << 7, rx = r & 7;
      i32x4 lo = *(const i32x4*)&Bs[rb_ + (((2 * g) ^ rx) << 4)];
      i32x4 hi = *(const i32x4*)&Bs[rb_ + (((2 * g + 1) ^ rx) << 4)];
      bfr[n][0] = lo[0]; bfr[n][1] = lo[1]; bfr[n][2] = lo[2]; bfr[n][3] = lo[3];
      bfr[n][4] = hi[0]; bfr[n][5] = hi[1]; bfr[n][6] = hi[2]; bfr[n][7] = hi[3];
    }
#pragma unroll
    for (int m = 0; m < 4; m++) {
      const int r = wr * 64 + m * 16 + lr;
      const int rb_ = r << 7, rx = r & 7;
      i32x4 lo = *(const i32x4*)&As[rb_ + (((2 * g) ^ rx) << 4)];
      i32x4 hi = *(const i32x4*)&As[rb_ + (((2 * g + 1) ^ rx) << 4)];
      i32x8 av;
      av[0] = lo[0]; av[1] = lo[1]; av[2] = lo[2]; av[3] = lo[3];
      av[4] = hi[0]; av[5] = hi[1]; av[6] = hi[2]; av[7] = hi[3];
#pragma unroll
      for (int n = 0; n < 4; n++)
        acc[m][n] = __builtin_amdgcn_mfma_scale_f32_16x16x128_f8f6f4(
            av, bfr[n], acc[m][n], 0, 0, 0, 127, 0, 127);
    }
  }

  const int rb = tm * 128 + wr * 64 + (lane >> 4) * 4;
  const int cb = tn * 128 + wc * 64 + lr;
  const float rs = 1.0f / 256.0f;
#pragma unroll
  for (int m = 0; m < 4; m++) {
#pragma unroll
    for (int n = 0; n < 4; n++) {
      const int gj = cb + n * 16;
#pragma unroll
      for (int r = 0; r < 4; r++) {
        const int gi = rb + m * 16 + r;
        float o = (gj < CENT_D) ? __expf(acc[m][n][r] * rs + p.bias[gj]) : 0.f;
        p.obf[(size_t)gi * p.ldo + gj] = f2bf(o);
      }
    }
  }
}

// ---------------------------------------------------------------------------
// Fused cast+pad of x, centres, w1, kern (bf16). Chunk = 4 dst bf16.
// Boundaries: x 786432 | cen 798720 | w1 929792 | kern 1060864 -> 4144 blocks.
// ---------------------------------------------------------------------------
__global__ __launch_bounds__(256) void prep_cast(
    const float* __restrict__ x, const float* __restrict__ cen,
    const float* __restrict__ w1, const float* __restrict__ kern,
    unsigned short* __restrict__ x_bf, unsigned short* __restrict__ c_bf,
    unsigned short* __restrict__ w1p, unsigned short* __restrict__ kernp) {
  const int c = blockIdx.x * 256 + threadIdx.x;
  const float* src; unsigned short* dst; int R, C, cpq, local, vec;
  if (c < 786432)       { src = x;    dst = x_bf;  R = 16384; C = 151;  cpq = 48;  local = c;           vec = 0; }
  else if (c < 798720)  { src = cen;  dst = c_bf;  R = 200;   C = 151;  cpq = 48;  local = c - 786432;  vec = 0; }
  else if (c < 929792)  { src = w1;   dst = w1p;   R = 2000;  C = 200;  cpq = 64;  local = c - 798720;  vec = 1; }
  else                  { src = kern; dst = kernp; R = 151;   C = 2000; cpq = 512; local = c - 929792;  vec = 1; }
  const int r  = local / cpq;
  const int c4 = (local - r * cpq) << 2;
  us4 o;
  if (vec && r < R && c4 + 3 < C) {
    f4 v = *(const f4*)&src[(size_t)r * C + c4];
    o[0] = f2bf(v[0]); o[1] = f2bf(v[1]); o[2] = f2bf(v[2]); o[3] = f2bf(v[3]);
  } else {
#pragma unroll
    for (int k = 0; k < 4; k++) {
      float v = (r < R && c4 + k < C) ? src[(size_t)r * C + c4 + k] : 0.f;
      o[k] = f2bf(v);
    }
  }
  *(us4*)&dst[(size_t)local * 4] = o;
}

// w2 (2000x2000) -> fp8 e4m3 (2048x2048), scaled by 2^8. 4096 blocks.
__global__ __launch_bounds__(256) void cast_fp8(
    const float* __restrict__ src, unsigned char* __restrict__ dst) {
  const int i = blockIdx.x * 256 + threadIdx.x;   // uchar4 index
  const int r = i >> 9;                            // 512 quads per 2048-row
  const int c4 = (i & 511) << 2;
  float v0 = 0.f, v1 = 0.f, v2 = 0.f, v3 = 0.f;
  if (r < 2000 && c4 + 3 < 2000) {
    f4 v = *(const f4*)&src[(size_t)r * 2000 + c4];
    v0 = v[0] * 256.f; v1 = v[1] * 256.f; v2 = v[2] * 256.f; v3 = v[3] * 256.f;
  } else if (r < 2000) {
    if (c4 + 0 < 2000) v0 = src[(size_t)r * 2000 + c4 + 0] * 256.f;
    if (c4 + 1 < 2000) v1 = src[(size_t)r * 2000 + c4 + 1] * 256.f;
    if (c4 + 2 < 2000) v2 = src[(size_t)r * 2000 + c4 + 2] * 256.f;
    if (c4 + 3 < 2000) v3 = src[(size_t)r * 2000 + c4 + 3] * 256.f;
  }
  int p0 = __builtin_amdgcn_cvt_pk_fp8_f32(v0, v1, 0, false);
  int p1 = __builtin_amdgcn_cvt_pk_fp8_f32(v2, v3, 0, false);
  unsigned int packed = ((unsigned)p0 & 0xFFFFu) | (((unsigned)p1 & 0xFFFFu) << 16);
  *(unsigned int*)&dst[(size_t)i * 4] = packed;
}

// ---------------------------------------------------------------------------
// Fused rownorm(x) + rownorm(centres) + sigmas^2.
// ---------------------------------------------------------------------------
__global__ __launch_bounds__(256) void prep_misc(
    const float* __restrict__ x, const float* __restrict__ cen,
    const float* __restrict__ sg,
    float* __restrict__ x2, float* __restrict__ c2, float* __restrict__ sg2) {
  const int b = blockIdx.x;
  if (b == 4160) {
    int j = threadIdx.x;
    sg2[j] = (j < HID_D) ? sg[j] * sg[j] : 0.f;
    return;
  }
  const float* src; float* dst; int R, base;
  if (b < 4096) { src = x;   dst = x2; R = BDIM;  base = b * 4; }
  else          { src = cen; dst = c2; R = HID_D; base = (b - 4096) * 4; }
  const int row = base + (threadIdx.x >> 6);
  const int l = threadIdx.x & 63;
  float s = 0.f;
  if (row < R)
    for (int k = l; k < IN_D; k += 64) { float v = src[(size_t)row * IN_D + k]; s += v * v; }
#pragma unroll
  for (int off = 32; off > 0; off >>= 1) s += __shfl_down(s, off);
  if (l == 0) dst[row] = s;
}

// ---------------------------------------------------------------------------
// d_out layout: [Ehat2 B*151][Rhat B*2000][Ehat2 B*151][Rhat B*2000][x B*151]
// ---------------------------------------------------------------------------
__global__ __launch_bounds__(256) void finalize(
    float* __restrict__ dout, const unsigned short* __restrict__ outp,
    const float* __restrict__ x, const float* __restrict__ part) {
  const int i = blockIdx.x;
  const size_t SL = (size_t)BDIM * IN_D;
  float* Eh = dout;
  float* Ra = dout + SL;
  float* Eb = dout + SL + (size_t)BDIM * CENT_D;
  float* Rb = Eb + SL;
  float* xo = Rb + (size_t)BDIM * CENT_D;
  const size_t ib = (size_t)i * IN_D;
  const float e0 = part[ib] + part[SL + ib] + part[2 * SL + ib] + part[3 * SL + ib];
  const float s = 1.f / e0;
  const int t = threadIdx.x;
  if (t < IN_D) {
    float v = (part[ib + t] + part[SL + ib + t] + part[2 * SL + ib + t] + part[3 * SL + ib + t]) * s;
    Eh[ib + t] = v;
    Eb[ib + t] = v;
    xo[ib + t] = x[ib + t];
  }
  if (t < 250) {
    const us8 u = *(const us8*)&outp[(size_t)i * CENTP + t * 8];
    f4 a, b;
#pragma unroll
    for (int k = 0; k < 4; k++) a[k] = bf2f(u[k]) * s;
#pragma unroll
    for (int k = 0; k < 4; k++) b[k] = bf2f(u[4 + k]) * s;
    const size_t o = (size_t)i * CENT_D + t * 8;
    *(f4*)&Ra[o] = a; *(f4*)&Ra[o + 4] = b;
    *(f4*)&Rb[o] = a; *(f4*)&Rb[o + 4] = b;
  }
}

extern "C" void kernel_launch(void* const* d_in, const int* in_sizes, int n_in,
                              void* d_out, int out_size, void* d_ws, size_t ws_size,
                              hipStream_t stream) {
  (void)in_sizes; (void)n_in; (void)out_size; (void)ws_size;
  const float* x       = (const float*)d_in[0];
  const float* centres = (const float*)d_in[1];
  const float* sigmas  = (const float*)d_in[2];
  const float* w1      = (const float*)d_in[3];
  const float* b1      = (const float*)d_in[4];
  const float* w2      = (const float*)d_in[5];
  const float* b2      = (const float*)d_in[6];
  const float* kern    = (const float*)d_in[7];
  float* dout = (float*)d_out;

  char* ws = (char*)d_ws;
  size_t off = 0;
  auto alloc = [&](size_t bytes) {
    char* p = ws + off;
    off = (off + bytes + 255) & ~(size_t)255;
    return p;
  };
  unsigned short* x_bf  = (unsigned short*)alloc((size_t)BDIM * INP * 2);
  unsigned short* c_bf  = (unsigned short*)alloc((size_t)KERNR * INP * 2);
  unsigned short* w1p   = (unsigned short*)alloc((size_t)CENTP * HIDP * 2);
  unsigned char*  w2p8  = (unsigned char*)alloc((size_t)CENTP * CENTP);
  unsigned short* kernp = (unsigned short*)alloc((size_t)KERNR * CENTP * 2);
  unsigned short* phip  = (unsigned short*)alloc((size_t)BDIM * HIDP * 2);
  unsigned short* outp  = (unsigned short*)alloc((size_t)BDIM * CENTP * 2);
  float* x2  = (float*)alloc((size_t)BDIM * 4);
  float* c2  = (float*)alloc((size_t)KERNR * 4);
  float* sg2 = (float*)alloc((size_t)KERNR * 4);
  float* eparts = (float*)alloc((size_t)4 * BDIM * IN_D * 4);
  // h (fp8, B x 2048 = 33.5 MB) lives in the Rhat_b output slot (131 MB);
  // consumed by GEMM2, overwritten by finalize at the end.
  unsigned char* hp8 = (unsigned char*)(dout + (size_t)BDIM * (2 * IN_D + CENT_D));

  prep_cast<<<4144, 256, 0, stream>>>(x, centres, w1, kern, x_bf, c_bf, w1p, kernp);
  cast_fp8<<<4096, 256, 0, stream>>>(w2, w2p8);
  prep_misc<<<4161, 256, 0, stream>>>(x, centres, sigmas, x2, c2, sg2);

  // GEMM0: phi  (M=16384, N=256, K=192)
  GArgs g0{}; g0.A = x_bf; g0.B = c_bf; g0.K = INP; g0.kspan = INP;
  g0.x2 = x2; g0.c2 = c2; g0.sg2 = sg2; g0.obf = phip; g0.ldo = HIDP;
  gemm_bt<0><<<dim3(BDIM / 128, HIDP / 128, 1), 256, 0, stream>>>(g0);

  // GEMM1: h = relu(phi @ w1^T + b1) -> fp8  (M=16384, N=2048, K=256)
  GArgs g1{}; g1.A = phip; g1.B = w1p; g1.K = HIDP; g1.kspan = HIDP;
  g1.bias = b1; g1.o8 = hp8; g1.ldo = CENTP;
  gemm_bt<1><<<dim3(BDIM / 128, CENTP / 128, 1), 256, 0, stream>>>(g1);

  // GEMM2: out = exp((h @ (256*w2)^T) * 2^-8 + b2)  (MX-fp8, K=2048)
  G8Args g2{}; g2.A = hp8; g2.B = w2p8; g2.K = CENTP;
  g2.bias = b2; g2.obf = outp; g2.ldo = CENTP;
  gemm_fp8<<<dim3(BDIM / 128, CENTP / 128), 256, 0, stream>>>(g2);

  // GEMM3: Ehat partials, split-K x4 (1024 blocks)
  GArgs g3{}; g3.A = outp; g3.B = kernp; g3.K = CENTP; g3.kspan = CENTP / 4;
  g3.of = eparts;
  gemm_bt<3><<<dim3(BDIM / 128, KERNR / 128, 4), 256, 0, stream>>>(g3);

  finalize<<<BDIM, 256, 0, stream>>>(dout, outp, x, eparts);
}